// Round 1
// baseline (240.745 us; speedup 1.0000x reference)
//
#include <hip/hip_runtime.h>

#define NSC 64      // Ns
#define NWN 12      // nw
#define LWN 6       // lw
#define NZD 200     // Nz
#define NSTEPS 40   // (lw-1)*SPD
#define NFRAMES 6

__global__ __launch_bounds__(256) void nnpzd_kernel(
    const float* __restrict__ Kz, const float* __restrict__ I0,
    const float* __restrict__ alpha_p, const float* __restrict__ Xi_p,
    const float* __restrict__ rho_p, const float* __restrict__ gamma_p,
    const float* __restrict__ Gamma_p, const float* __restrict__ varphi_p,
    const float* __restrict__ omega_p, const float* __restrict__ beta_p,
    const float* __restrict__ NO3_0, const float* __restrict__ NH4_0,
    const float* __restrict__ P_0, const float* __restrict__ Z_0,
    const float* __restrict__ D_0, const float* __restrict__ subw,
    const float* __restrict__ zT, const float* __restrict__ zw,
    float* __restrict__ out)
{
    const float XI = 0.067f, ZETA = 0.0095f, LAM = 0.06f, PSI = 1.46f;
    const float MU = 0.25f, ETA = 1.5f, KAP = 1.0f, DT = 0.125f;

    const int col = blockIdx.x;        // 0..767, one column per block
    const int si  = col / NWN;         // scenario
    const int wi  = col - si * NWN;    // window
    const int tid = threadIdx.x;
    const bool rowOK = (tid < NZD);

    __shared__ float zTl[NZD];
    __shared__ float dzTl[NZD];
    __shared__ float dzwl[NZD + 1];
    __shared__ float Ab[2][NZD];
    __shared__ float Bb[2][NZD];
    __shared__ float Cb[2][NZD];
    __shared__ float Db[2][5 * NZD];
    __shared__ float scanb[2][256];
    __shared__ float fluxl[NZD + 1];

    // geometry
    for (int i = tid; i < NZD; i += 256) {
        zTl[i]  = zT[i];
        dzTl[i] = zw[i + 1] - zw[i];
    }
    for (int i = tid; i <= NZD; i += 256) {
        float v;
        if (i == 0)        v = 0.5f * (zw[1] - zw[0]);
        else if (i == NZD) v = 0.5f * (zw[NZD] - zw[NZD - 1]);
        else               v = zT[i] - zT[i - 1];
        dzwl[i] = v;
    }

    // per-scenario scalars
    const float pa   = alpha_p[si];
    const float pXi  = Xi_p[si];
    const float prho = rho_p[si];
    const float pgam = gamma_p[si];
    const float pGam = Gamma_p[si];
    const float pvar = varphi_p[si];
    const float sedc = omega_p[si];
    const float pbet = beta_p[si];
    const int   sw0  = (int)subw[wi * LWN];   // sub_windows[w,0]

    // initial state in registers
    const size_t ibase = ((size_t)si * NWN + wi) * NZD;
    float vN = 0.f, vA = 0.f, vP = 0.f, vZ = 0.f, vD = 0.f;
    if (rowOK) {
        vN = NO3_0[ibase + tid];
        vA = NH4_0[ibase + tid];
        vP = P_0[ibase + tid];
        vZ = Z_0[ibase + tid];
        vD = D_0[ibase + tid];
    }

    // frame 0 = initial condition; out[s][w][frame][tracer][z]
    {
        const size_t ob = (((size_t)si * NWN + wi) * NFRAMES + 0) * (5 * (size_t)NZD);
        if (rowOK) {
            out[ob + 0 * NZD + tid] = vN;
            out[ob + 1 * NZD + tid] = vA;
            out[ob + 2 * NZD + tid] = vP;
            out[ob + 3 * NZD + tid] = vZ;
            out[ob + 4 * NZD + tid] = vD;
        }
    }
    __syncthreads();

    const float* KzBase = Kz + (size_t)si * (2 * NWN * LWN + 2) * (NZD + 1);
    const float* I0row  = I0 + (size_t)si * (NWN * LWN + 1);

    for (int k = 0; k < NSTEPS; ++k) {
        const int day  = k >> 3;   // k // SPD
        const int hh   = k >> 2;   // k // (SPD/2)
        const int sidx = day + 1;

        // ---- inclusive scan of P*dzT (Hillis-Steele, double-buffered) ----
        float csum = rowOK ? vP * dzTl[tid] : 0.f;
        int pp = 0;
        #pragma unroll
        for (int off = 1; off < NZD; off <<= 1) {
            scanb[pp][tid] = csum;
            __syncthreads();
            if (tid >= off) csum += scanb[pp][tid - off];
            pp ^= 1;
        }

        // ---- bio tendencies + RHS (registers only) ----
        float r0 = 0.f, r1 = 0.f, r2 = 0.f, r3 = 0.f, r4 = 0.f;
        if (rowOK) {
            const float I0d = I0row[sw0 + day];
            const float It  = I0d * expf(-XI * zTl[tid] - ZETA * csum);
            const float aIt = pa * It;
            const float G   = ETA * aIt / sqrtf(ETA * ETA + aIt * aIt);
            const float fN  = vN / (KAP + vN);
            const float fA  = vA / (KAP + vA);
            const float eP  = expf(-PSI * vA);
            const float graz = prho * (1.f - expf(-LAM * vP)) * vZ;
            const float bN = MU * vA - G * eP * vP * fN;
            const float bA = pvar * vD + pGam * vZ - G * vP * fA - MU * vA;
            const float bP = G * vP * (eP * fN + fA) - graz - pXi * vP;
            const float bZ = (1.f - pgam) * graz - pGam * vZ;
            const float bD = pgam * graz + pXi * vP - pvar * vD;
            r0 = vN + DT * bN;
            r1 = vA + DT * bA;
            r2 = vP + DT * bP;
            r3 = vZ + DT * bZ;
            r4 = vD + DT * bD;
        }

        // ---- tridiagonal coefficients ----
        // row i: a_i*x[i-1] + b_i*x[i] + c_i*x[i+1] = r_i
        float ai = 0.f, bi = 1.f, ci = 0.f;
        if (rowOK) {
            const float* kzp = KzBase + (size_t)(2 * sw0 + hh) * (NZD + 1);
            const float ainf = (tid >= 1)
                ? -DT * kzp[tid] / (dzTl[tid] * dzwl[tid]) : 0.f;
            const float asup = (tid <= NZD - 2)
                ? -DT * kzp[tid + 1] / (dzTl[tid] * dzwl[tid + 1]) : 0.f;
            ai = ainf;
            ci = asup;
            bi = 1.f - ainf - asup;   // strictly diagonally dominant
            Ab[0][tid] = ai; Bb[0][tid] = bi; Cb[0][tid] = ci;
            Db[0][0 * NZD + tid] = r0;
            Db[0][1 * NZD + tid] = r1;
            Db[0][2 * NZD + tid] = r2;
            Db[0][3 * NZD + tid] = r3;
            Db[0][4 * NZD + tid] = r4;
        }
        __syncthreads();

        // ---- PCR: 8 stride-doubling steps fully decouple n=200 rows ----
        int p = 0;
        #pragma unroll
        for (int off = 1; off < NZD; off <<= 1) {
            if (rowOK) {
                float al = 0.f, ga = 0.f;
                float am = 0.f, bm = 1.f, cm = 0.f;
                float dm0 = 0.f, dm1 = 0.f, dm2 = 0.f, dm3 = 0.f, dm4 = 0.f;
                float ap2 = 0.f, bp2 = 1.f, cp2 = 0.f;
                float dq0 = 0.f, dq1 = 0.f, dq2 = 0.f, dq3 = 0.f, dq4 = 0.f;
                if (tid >= off) {
                    const int j = tid - off;
                    am = Ab[p][j]; bm = Bb[p][j]; cm = Cb[p][j];
                    dm0 = Db[p][0 * NZD + j]; dm1 = Db[p][1 * NZD + j];
                    dm2 = Db[p][2 * NZD + j]; dm3 = Db[p][3 * NZD + j];
                    dm4 = Db[p][4 * NZD + j];
                    al = -ai / bm;
                }
                if (tid + off < NZD) {
                    const int j = tid + off;
                    ap2 = Ab[p][j]; bp2 = Bb[p][j]; cp2 = Cb[p][j];
                    dq0 = Db[p][0 * NZD + j]; dq1 = Db[p][1 * NZD + j];
                    dq2 = Db[p][2 * NZD + j]; dq3 = Db[p][3 * NZD + j];
                    dq4 = Db[p][4 * NZD + j];
                    ga = -ci / bp2;
                }
                const float na = al * am;
                const float nc = ga * cp2;
                const float nb = bi + al * cm + ga * ap2;
                r0 += al * dm0 + ga * dq0;
                r1 += al * dm1 + ga * dq1;
                r2 += al * dm2 + ga * dq2;
                r3 += al * dm3 + ga * dq3;
                r4 += al * dm4 + ga * dq4;
                ai = na; bi = nb; ci = nc;
                const int q = p ^ 1;
                Ab[q][tid] = ai; Bb[q][tid] = bi; Cb[q][tid] = ci;
                Db[q][0 * NZD + tid] = r0;
                Db[q][1 * NZD + tid] = r1;
                Db[q][2 * NZD + tid] = r2;
                Db[q][3 * NZD + tid] = r3;
                Db[q][4 * NZD + tid] = r4;
            }
            __syncthreads();
            p ^= 1;
        }

        // ---- back out solution; stage D for sediment flux ----
        float xN = 0.f, xA = 0.f, xP = 0.f, xZ = 0.f, xD = 0.f;
        if (rowOK) {
            const float invb = 1.f / bi;
            xN = r0 * invb; xA = r1 * invb; xP = r2 * invb;
            xZ = r3 * invb; xD = r4 * invb;
            scanb[0][tid] = xD;   // reuse scan buffer (safe: last scan read was 9+ barriers ago)
        }
        __syncthreads();

        // ---- WENO3-Z sediment flux at interfaces 0..NZ ----
        if (tid <= NZD) {
            float f;
            if (tid == 0)        f = 0.f;
            else if (tid == 1)   f = sedc * scanb[0][0];
            else if (tid == NZD) f = sedc * scanb[0][NZD - 1];
            else {
                const float qm = scanb[0][tid - 2] * dzTl[tid - 2];
                const float q0 = scanb[0][tid - 1] * dzTl[tid - 1];
                const float qp = scanb[0][tid]     * dzTl[tid];
                const float qi1 = -0.5f * qm + 1.5f * q0;
                const float qi2 = 0.5f * (q0 + qp);
                const float b1 = (q0 - qm) * (q0 - qm);
                const float b2 = (qp - q0) * (qp - q0);
                const float tau = fabsf(b2 - b1);
                const float w1 = (1.f / 3.f) * (1.f + tau / (b1 + 1e-14f));
                const float w2 = (2.f / 3.f) * (1.f + tau / (b2 + 1e-14f));
                f = sedc * ((w1 * qi1 + w2 * qi2) / (w1 + w2)) / dzwl[tid];
            }
            fluxl[tid] = f;
        }
        __syncthreads();

        // ---- sediment update + NO3 relaxation; commit new state ----
        if (rowOK) {
            const float sD = xD + DT * (fluxl[tid] - fluxl[tid + 1]) / dzTl[tid];
            const float sw = subw[wi * LWN + sidx];
            // rw = (relu(sw-30)-relu(sw-31)-relu(sw-60)+relu(sw-61))/20
            const float rap = 0.05f * (fminf(fmaxf(sw - 30.f, 0.f), 1.f)
                                     - fminf(fmaxf(sw - 60.f, 0.f), 1.f));
            vN = xN + (pbet - xN) * rap;
            vA = xA; vP = xP; vZ = xZ; vD = sD;

            if (((k + 1) & 7) == 0) {
                const int fr = (k + 1) >> 3;
                const size_t ob =
                    (((size_t)si * NWN + wi) * NFRAMES + fr) * (5 * (size_t)NZD);
                out[ob + 0 * NZD + tid] = vN;
                out[ob + 1 * NZD + tid] = vA;
                out[ob + 2 * NZD + tid] = vP;
                out[ob + 3 * NZD + tid] = vZ;
                out[ob + 4 * NZD + tid] = vD;
            }
        }
        __syncthreads();
    }
}

extern "C" void kernel_launch(void* const* d_in, const int* in_sizes, int n_in,
                              void* d_out, int out_size, void* d_ws, size_t ws_size,
                              hipStream_t stream) {
    const float* Kz    = (const float*)d_in[0];
    const float* I0    = (const float*)d_in[1];
    const float* alpha = (const float*)d_in[2];
    const float* Xi    = (const float*)d_in[3];
    const float* rho   = (const float*)d_in[4];
    const float* gam   = (const float*)d_in[5];
    const float* Gam   = (const float*)d_in[6];
    const float* varp  = (const float*)d_in[7];
    const float* omg   = (const float*)d_in[8];
    const float* bet   = (const float*)d_in[9];
    const float* N0    = (const float*)d_in[10];
    const float* A0    = (const float*)d_in[11];
    const float* P0    = (const float*)d_in[12];
    const float* Z0    = (const float*)d_in[13];
    const float* Dd0   = (const float*)d_in[14];
    const float* sbw   = (const float*)d_in[15];
    const float* zTp   = (const float*)d_in[16];
    const float* zwp   = (const float*)d_in[17];
    float* out = (float*)d_out;

    dim3 grid(NSC * NWN);   // 768 independent columns
    dim3 block(256);
    hipLaunchKernelGGL(nnpzd_kernel, grid, block, 0, stream,
                       Kz, I0, alpha, Xi, rho, gam, Gam, varp, omg, bet,
                       N0, A0, P0, Z0, Dd0, sbw, zTp, zwp, out);
}

// Round 2
// 160.844 us; speedup vs baseline: 1.4968x; 1.4968x over previous
//
#include <hip/hip_runtime.h>

#define NSC 64      // Ns
#define NWN 12      // nw
#define LWN 6       // lw
#define NZD 200     // Nz
#define NSTEPS 40   // (lw-1)*SPD
#define NFRAMES 6
#define NL 4        // cells per lane
#define ACTL 50     // active lanes (50*4 = 200)

__device__ __forceinline__ float weno3z_f(float qm, float q0, float qp) {
    const float qi1 = -0.5f * qm + 1.5f * q0;
    const float qi2 = 0.5f * (q0 + qp);
    const float b1 = (q0 - qm) * (q0 - qm);
    const float b2 = (qp - q0) * (qp - q0);
    const float tau = fabsf(b2 - b1);
    const float w1 = (1.f / 3.f) * (1.f + tau / (b1 + 1e-14f));
    const float w2 = (2.f / 3.f) * (1.f + tau / (b2 + 1e-14f));
    return (w1 * qi1 + w2 * qi2) / (w1 + w2);
}

__global__ __launch_bounds__(64) void nnpzd_wave(
    const float* __restrict__ Kz, const float* __restrict__ I0,
    const float* __restrict__ alpha_p, const float* __restrict__ Xi_p,
    const float* __restrict__ rho_p, const float* __restrict__ gamma_p,
    const float* __restrict__ Gamma_p, const float* __restrict__ varphi_p,
    const float* __restrict__ omega_p, const float* __restrict__ beta_p,
    const float* __restrict__ NO3_0, const float* __restrict__ NH4_0,
    const float* __restrict__ P_0, const float* __restrict__ Z_0,
    const float* __restrict__ D_0, const float* __restrict__ subw,
    const float* __restrict__ zT, const float* __restrict__ zw,
    float* __restrict__ out)
{
    const float XI = 0.067f, ZETA = 0.0095f, LAM = 0.06f, PSI = 1.46f;
    const float MU = 0.25f, ETA = 1.5f, KAP = 1.0f, DT = 0.125f;

    const int col  = blockIdx.x;            // one column per wave
    const int si   = col / NWN;
    const int wi   = col - si * NWN;
    const int lane = threadIdx.x;           // blockDim = 64 = one wave
    const bool act = lane < ACTL;
    const int  c0  = lane * NL;             // first global cell of this lane

    const float pa   = alpha_p[si];
    const float pXi  = Xi_p[si];
    const float prho = rho_p[si];
    const float pgam = gamma_p[si];
    const float pGam = Gamma_p[si];
    const float pvar = varphi_p[si];
    const float sedc = omega_p[si];
    const float pbet = beta_p[si];
    const int   sw0  = (int)subw[wi * LWN];

    // ---- geometry (per-lane registers; inactive lanes get safe dummies) ----
    float zTl[NL], dzT[NL], dzw[NL + 1];
    #pragma unroll
    for (int j = 0; j < NL; ++j) {
        const int i = act ? (c0 + j) : 0;
        zTl[j] = zT[i];
        dzT[j] = zw[i + 1] - zw[i];
    }
    #pragma unroll
    for (int j = 0; j <= NL; ++j) {
        const int i = act ? (c0 + j) : 0;
        dzw[j] = (i == 0)    ? 0.5f * (zw[1] - zw[0])
               : (i >= NZD)  ? 0.5f * (zw[NZD] - zw[NZD - 1])
                             : (zT[i] - zT[i - 1]);
    }

    // ---- initial state in registers ----
    float vN[NL], vA[NL], vP[NL], vZ[NL], vD[NL];
    {
        const size_t ib = (size_t)col * NZD + c0;
        #pragma unroll
        for (int j = 0; j < NL; ++j) {
            vN[j] = act ? NO3_0[ib + j] : 0.f;
            vA[j] = act ? NH4_0[ib + j] : 0.f;
            vP[j] = act ? P_0[ib + j]  : 0.f;
            vZ[j] = act ? Z_0[ib + j]  : 0.f;
            vD[j] = act ? D_0[ib + j]  : 0.f;
        }
    }

    // frame 0
    const size_t obase = (size_t)col * (NFRAMES * 5 * NZD);
    if (act) {
        #pragma unroll
        for (int j = 0; j < NL; ++j) {
            out[obase + 0 * NZD + c0 + j] = vN[j];
            out[obase + 1 * NZD + c0 + j] = vA[j];
            out[obase + 2 * NZD + c0 + j] = vP[j];
            out[obase + 3 * NZD + c0 + j] = vZ[j];
            out[obase + 4 * NZD + c0 + j] = vD[j];
        }
    }

    const float* KzBase = Kz + (size_t)si * (2 * NWN * LWN + 2) * (NZD + 1);
    const float* I0row  = I0 + (size_t)si * (NWN * LWN + 1);

    float ac[NL], cc[NL];          // tridiag sub/sup per cell (cached 4 steps)
    float I0d = 0.f, rap = 0.f;
    const int lp1 = (lane < 63) ? lane + 1 : 63;
    const int lm1 = (lane > 0) ? lane - 1 : 0;

    for (int k = 0; k < NSTEPS; ++k) {
        const int day = k >> 3, hh = k >> 2;

        if ((k & 3) == 0) {   // Kz row changes every 4 steps
            const float* kzp = KzBase + (size_t)(2 * sw0 + hh) * (NZD + 1);
            float kzv[NL + 1];
            #pragma unroll
            for (int j = 0; j <= NL; ++j) kzv[j] = act ? kzp[c0 + j] : 0.f;
            #pragma unroll
            for (int j = 0; j < NL; ++j) {
                const int i = c0 + j;
                ac[j] = (act && i >= 1)       ? -DT * kzv[j]     / (dzT[j] * dzw[j])     : 0.f;
                cc[j] = (act && i <= NZD - 2) ? -DT * kzv[j + 1] / (dzT[j] * dzw[j + 1]) : 0.f;
            }
        }
        if ((k & 7) == 0) {   // I0 / relaxation change every 8 steps
            I0d = I0row[sw0 + day];
            const float sw = subw[wi * LWN + day + 1];
            rap = 0.05f * (fminf(fmaxf(sw - 30.f, 0.f), 1.f)
                         - fminf(fmaxf(sw - 60.f, 0.f), 1.f));
        }

        // ---- inclusive cumsum of P*dzT: local prefix + wave scan (no barriers) ----
        float cloc[NL];
        float run = 0.f;
        #pragma unroll
        for (int j = 0; j < NL; ++j) { run += act ? vP[j] * dzT[j] : 0.f; cloc[j] = run; }
        float pref = run;
        #pragma unroll
        for (int off = 1; off < 64; off <<= 1) {
            const float t = __shfl_up(pref, off, 64);
            if (lane >= off) pref += t;
        }
        pref -= run;   // exclusive prefix of lane totals

        // ---- bio tendencies + RHS ----
        float dd[5][NL];
        #pragma unroll
        for (int j = 0; j < NL; ++j) {
            const float csum = pref + cloc[j];
            const float It   = I0d * expf(-XI * zTl[j] - ZETA * csum);
            const float aIt  = pa * It;
            const float G    = ETA * aIt / sqrtf(ETA * ETA + aIt * aIt);
            const float fN   = vN[j] / (KAP + vN[j]);
            const float fA   = vA[j] / (KAP + vA[j]);
            const float eP   = expf(-PSI * vA[j]);
            const float graz = prho * (1.f - expf(-LAM * vP[j])) * vZ[j];
            const float bN = MU * vA[j] - G * eP * vP[j] * fN;
            const float bA = pvar * vD[j] + pGam * vZ[j] - G * vP[j] * fA - MU * vA[j];
            const float bP = G * vP[j] * (eP * fN + fA) - graz - pXi * vP[j];
            const float bZ = (1.f - pgam) * graz - pGam * vZ[j];
            const float bD = pgam * graz + pXi * vP[j] - pvar * vD[j];
            dd[0][j] = vN[j] + DT * bN;
            dd[1][j] = vA[j] + DT * bA;
            dd[2][j] = vP[j] + DT * bP;
            dd[3][j] = vZ[j] + DT * bZ;
            dd[4][j] = vD[j] + DT * bD;
        }

        // ---- per-lane Thomas forward sweep: x_j = D_j - A_j*xm - C_j*x_{j+1} ----
        // (xm = last cell of previous lane; inactive lanes have a=c=0,b=1)
        float A[NL], C[NL], Dt[5][NL];
        {
            const float b0  = 1.f - ac[0] - cc[0];
            const float inv = 1.f / b0;
            A[0] = ac[0] * inv; C[0] = cc[0] * inv;
            #pragma unroll
            for (int t = 0; t < 5; ++t) Dt[t][0] = dd[t][0] * inv;
        }
        #pragma unroll
        for (int j = 1; j < NL; ++j) {
            const float bj  = 1.f - ac[j] - cc[j];
            const float m   = bj - ac[j] * C[j - 1];
            const float inv = 1.f / m;
            A[j] = -ac[j] * A[j - 1] * inv;
            C[j] = cc[j] * inv;
            #pragma unroll
            for (int t = 0; t < 5; ++t) Dt[t][j] = (dd[t][j] - ac[j] * Dt[t][j - 1]) * inv;
        }

        // ---- compose x0 = E - F*xm - G*x3 within own block ----
        float Fc = A[2], Gc = C[2], Ec[5];
        #pragma unroll
        for (int t = 0; t < 5; ++t) Ec[t] = Dt[t][2];
        Fc = A[1] - C[1] * Fc; Gc = -C[1] * Gc;
        #pragma unroll
        for (int t = 0; t < 5; ++t) Ec[t] = Dt[t][1] - C[1] * Ec[t];
        Fc = A[0] - C[0] * Fc; Gc = -C[0] * Gc;
        #pragma unroll
        for (int t = 0; t < 5; ++t) Ec[t] = Dt[t][0] - C[0] * Ec[t];

        // ---- reduced 50-unknown tridiagonal in block-last cells ----
        // aR*y_{l-1} + bR*y_l + cR*y_{l+1} = dR
        const float Fn = __shfl(Fc, lp1, 64);
        const float Gn = __shfl(Gc, lp1, 64);
        float aR = A[NL - 1];
        const float C3 = C[NL - 1];
        float bR = 1.f - C3 * Fn;
        float cR = -C3 * Gn;
        float dR[5];
        #pragma unroll
        for (int t = 0; t < 5; ++t) {
            const float En = __shfl(Ec[t], lp1, 64);
            dR[t] = Dt[t][NL - 1] - C3 * En;
        }
        if (!act) {
            aR = 0.f; bR = 1.f; cR = 0.f;
            #pragma unroll
            for (int t = 0; t < 5; ++t) dR[t] = 0.f;
        }

        // ---- shuffle-PCR, 6 rounds (64 >= 50) ----
        #pragma unroll
        for (int off = 1; off < 64; off <<= 1) {
            const int sm = lane - off, sp = lane + off;
            const bool vmv = (sm >= 0), vpv = (sp < 64);
            const int smc = vmv ? sm : 0, spc = vpv ? sp : 63;
            const float ib = 1.f / bR;           // one divide per round
            float am = __shfl(aR, smc, 64), ibm = __shfl(ib, smc, 64), cm = __shfl(cR, smc, 64);
            float ap = __shfl(aR, spc, 64), ibp = __shfl(ib, spc, 64), cp2 = __shfl(cR, spc, 64);
            float dm[5], dp[5];
            #pragma unroll
            for (int t = 0; t < 5; ++t) { dm[t] = __shfl(dR[t], smc, 64); dp[t] = __shfl(dR[t], spc, 64); }
            if (!vmv) { am = 0.f; ibm = 1.f; cm = 0.f;
                #pragma unroll
                for (int t = 0; t < 5; ++t) dm[t] = 0.f; }
            if (!vpv) { ap = 0.f; ibp = 1.f; cp2 = 0.f;
                #pragma unroll
                for (int t = 0; t < 5; ++t) dp[t] = 0.f; }
            const float e1 = -aR * ibm;
            const float e2 = -cR * ibp;
            bR = bR + e1 * cm + e2 * ap;
            aR = e1 * am;
            cR = e2 * cp2;
            #pragma unroll
            for (int t = 0; t < 5; ++t) dR[t] += e1 * dm[t] + e2 * dp[t];
        }
        const float invb = 1.f / bR;
        float y[5];
        #pragma unroll
        for (int t = 0; t < 5; ++t) y[t] = dR[t] * invb;

        // ---- back-substitution within block ----
        float X[5][NL];
        #pragma unroll
        for (int t = 0; t < 5; ++t) {
            const float xm = __shfl(y[t], lm1, 64);   // lane 0: A[j]==0 kills xm
            X[t][NL - 1] = y[t];
            #pragma unroll
            for (int j = NL - 2; j >= 0; --j)
                X[t][j] = Dt[t][j] - A[j] * xm - C[j] * X[t][j + 1];
        }

        // ---- WENO3-Z sediment flux (3 halo shuffles) ----
        float q[NL];
        #pragma unroll
        for (int j = 0; j < NL; ++j) q[j] = X[4][j] * dzT[j];
        const float qm2 = __shfl(q[2], lm1, 64);   // cell c0-2
        const float qm1 = __shfl(q[3], lm1, 64);   // cell c0-1
        float f0, f1, f2, f3, f4;
        f0 = (lane == 0) ? 0.f             : sedc * weno3z_f(qm2, qm1, q[0]) / dzw[0];
        f1 = (lane == 0) ? sedc * X[4][0]  : sedc * weno3z_f(qm1, q[0], q[1]) / dzw[1];
        f2 = sedc * weno3z_f(q[0], q[1], q[2]) / dzw[2];
        f3 = sedc * weno3z_f(q[1], q[2], q[3]) / dzw[3];
        const float f0n = __shfl(f0, lp1, 64);
        f4 = (lane == ACTL - 1) ? sedc * X[4][NL - 1] : f0n;

        // ---- commit state (+NO3 relaxation), frame write every 8 steps ----
        const float fs[NL + 1] = { f0, f1, f2, f3, f4 };
        #pragma unroll
        for (int j = 0; j < NL; ++j) {
            const float sd = X[4][j] + DT * (fs[j] - fs[j + 1]) / dzT[j];
            vN[j] = X[0][j] + (pbet - X[0][j]) * rap;
            vA[j] = X[1][j]; vP[j] = X[2][j]; vZ[j] = X[3][j]; vD[j] = sd;
        }
        if (((k + 1) & 7) == 0 && act) {
            const int fr = (k + 1) >> 3;
            const size_t ob = obase + (size_t)fr * (5 * NZD) + c0;
            #pragma unroll
            for (int j = 0; j < NL; ++j) {
                out[ob + 0 * NZD + j] = vN[j];
                out[ob + 1 * NZD + j] = vA[j];
                out[ob + 2 * NZD + j] = vP[j];
                out[ob + 3 * NZD + j] = vZ[j];
                out[ob + 4 * NZD + j] = vD[j];
            }
        }
    }
}

extern "C" void kernel_launch(void* const* d_in, const int* in_sizes, int n_in,
                              void* d_out, int out_size, void* d_ws, size_t ws_size,
                              hipStream_t stream) {
    const float* Kz    = (const float*)d_in[0];
    const float* I0    = (const float*)d_in[1];
    const float* alpha = (const float*)d_in[2];
    const float* Xi    = (const float*)d_in[3];
    const float* rho   = (const float*)d_in[4];
    const float* gam   = (const float*)d_in[5];
    const float* Gam   = (const float*)d_in[6];
    const float* varp  = (const float*)d_in[7];
    const float* omg   = (const float*)d_in[8];
    const float* bet   = (const float*)d_in[9];
    const float* N0    = (const float*)d_in[10];
    const float* A0    = (const float*)d_in[11];
    const float* P0    = (const float*)d_in[12];
    const float* Z0    = (const float*)d_in[13];
    const float* Dd0   = (const float*)d_in[14];
    const float* sbw   = (const float*)d_in[15];
    const float* zTp   = (const float*)d_in[16];
    const float* zwp   = (const float*)d_in[17];
    float* out = (float*)d_out;

    dim3 grid(NSC * NWN);   // 768 waves = 3 blocks/CU exactly
    dim3 block(64);
    hipLaunchKernelGGL(nnpzd_wave, grid, block, 0, stream,
                       Kz, I0, alpha, Xi, rho, gam, Gam, varp, omg, bet,
                       N0, A0, P0, Z0, Dd0, sbw, zTp, zwp, out);
}

// Round 3
// 77.393 us; speedup vs baseline: 3.1107x; 2.0783x over previous
//
#include <hip/hip_runtime.h>

#define NSC 64      // Ns
#define NWN 12      // nw
#define LWN 6       // lw
#define NZD 200     // Nz
#define NSTEPS 40   // (lw-1)*SPD
#define NFRAMES 6
#define NL 4        // cells per lane
#define ACTL 50     // active lanes (50*4 = 200)

__device__ __forceinline__ float frcp(float x) { return __builtin_amdgcn_rcpf(x); }
__device__ __forceinline__ float frsq(float x) { return __builtin_amdgcn_rsqf(x); }
__device__ __forceinline__ float bperm(int addr, float v) {
    return __int_as_float(__builtin_amdgcn_ds_bpermute(addr, __float_as_int(v)));
}

// WENO3-Z with native reciprocals (error ~1ulp, far inside tolerance)
__device__ __forceinline__ float weno3z_f(float qm, float q0, float qp) {
    const float qi1 = -0.5f * qm + 1.5f * q0;
    const float qi2 = 0.5f * (q0 + qp);
    const float b1 = (q0 - qm) * (q0 - qm);
    const float b2 = (qp - q0) * (qp - q0);
    const float tau = fabsf(b2 - b1);
    const float w1 = (1.f / 3.f) * (1.f + tau * frcp(b1 + 1e-14f));
    const float w2 = (2.f / 3.f) * (1.f + tau * frcp(b2 + 1e-14f));
    return (w1 * qi1 + w2 * qi2) * frcp(w1 + w2);
}

__global__ __launch_bounds__(64) void nnpzd_wave(
    const float* __restrict__ Kz, const float* __restrict__ I0,
    const float* __restrict__ alpha_p, const float* __restrict__ Xi_p,
    const float* __restrict__ rho_p, const float* __restrict__ gamma_p,
    const float* __restrict__ Gamma_p, const float* __restrict__ varphi_p,
    const float* __restrict__ omega_p, const float* __restrict__ beta_p,
    const float* __restrict__ NO3_0, const float* __restrict__ NH4_0,
    const float* __restrict__ P_0, const float* __restrict__ Z_0,
    const float* __restrict__ D_0, const float* __restrict__ subw,
    const float* __restrict__ zT, const float* __restrict__ zw,
    float* __restrict__ out)
{
    const float XI = 0.067f, ZETA = 0.0095f, LAM = 0.06f, PSI = 1.46f;
    const float MU = 0.25f, ETA = 1.5f, KAP = 1.0f, DT = 0.125f;

    const int col  = blockIdx.x;            // one column per wave
    const int si   = col / NWN;
    const int wi   = col - si * NWN;
    const int lane = threadIdx.x;           // blockDim = 64 = one wave
    const bool act = lane < ACTL;
    const int  c0  = lane * NL;

    // ---- precomputed bpermute byte addresses (loop-invariant) ----
    const int aM1 = ((lane > 0) ? lane - 1 : 0) * 4;
    const int aP1 = ((lane < 63) ? lane + 1 : 63) * 4;
    int aUp[3], aDn[3], aSc[6];
    #pragma unroll
    for (int r = 0; r < 6; ++r) {
        const int off = 1 << r;
        aSc[r] = ((lane >= off) ? lane - off : 0) * 4;
        if (r < 3) {
            aUp[r] = aSc[r];
            aDn[r] = ((lane + off < 64) ? lane + off : 63) * 4;
        }
    }

    const float pa   = alpha_p[si];
    const float pXi  = Xi_p[si];
    const float prho = rho_p[si];
    const float pgam = gamma_p[si];
    const float pGam = Gamma_p[si];
    const float pvar = varphi_p[si];
    const float sedc = omega_p[si];
    const float pbet = beta_p[si];
    const int   sw0  = (int)subw[wi * LWN];

    // ---- per-lane constant geometry (precise one-time math) ----
    float dzT[NL], DTdz[NL], ezT[NL], kAf[NL], kCf[NL], swN[NL];
    {
        float dzw_[NL + 1];
        #pragma unroll
        for (int j = 0; j <= NL; ++j) {
            const int i = act ? (c0 + j) : 0;
            dzw_[j] = (i == 0)   ? 0.5f * (zw[1] - zw[0])
                    : (i >= NZD) ? 0.5f * (zw[NZD] - zw[NZD - 1])
                                 : (zT[i] - zT[i - 1]);
        }
        #pragma unroll
        for (int j = 0; j < NL; ++j) {
            const int i = act ? (c0 + j) : 0;
            const float dz = zw[i + 1] - zw[i];
            dzT[j]  = dz;
            DTdz[j] = act ? (DT / dz) : 0.f;
            ezT[j]  = expf(-XI * zT[i]);
            kAf[j]  = (act && (c0 + j) >= 1)       ? (-DT / (dz * dzw_[j]))     : 0.f;
            kCf[j]  = (act && (c0 + j) <= NZD - 2) ? (-DT / (dz * dzw_[j + 1])) : 0.f;
            swN[j]  = act ? (sedc / dzw_[j]) : 0.f;
        }
    }

    // ---- initial state (float4 loads) ----
    float vN[NL], vA[NL], vP[NL], vZ[NL], vD[NL];
    {
        const size_t ib = (size_t)col * NZD + c0;
        if (act) {
            const float4 n4 = *reinterpret_cast<const float4*>(&NO3_0[ib]);
            const float4 a4 = *reinterpret_cast<const float4*>(&NH4_0[ib]);
            const float4 p4 = *reinterpret_cast<const float4*>(&P_0[ib]);
            const float4 z4 = *reinterpret_cast<const float4*>(&Z_0[ib]);
            const float4 d4 = *reinterpret_cast<const float4*>(&D_0[ib]);
            vN[0]=n4.x; vN[1]=n4.y; vN[2]=n4.z; vN[3]=n4.w;
            vA[0]=a4.x; vA[1]=a4.y; vA[2]=a4.z; vA[3]=a4.w;
            vP[0]=p4.x; vP[1]=p4.y; vP[2]=p4.z; vP[3]=p4.w;
            vZ[0]=z4.x; vZ[1]=z4.y; vZ[2]=z4.z; vZ[3]=z4.w;
            vD[0]=d4.x; vD[1]=d4.y; vD[2]=d4.z; vD[3]=d4.w;
        } else {
            #pragma unroll
            for (int j = 0; j < NL; ++j) { vN[j]=vA[j]=vP[j]=vZ[j]=vD[j]=0.f; }
        }
    }

    // frame 0
    const size_t obase = (size_t)col * (NFRAMES * 5 * NZD);
    if (act) {
        *reinterpret_cast<float4*>(&out[obase + 0 * NZD + c0]) = make_float4(vN[0],vN[1],vN[2],vN[3]);
        *reinterpret_cast<float4*>(&out[obase + 1 * NZD + c0]) = make_float4(vA[0],vA[1],vA[2],vA[3]);
        *reinterpret_cast<float4*>(&out[obase + 2 * NZD + c0]) = make_float4(vP[0],vP[1],vP[2],vP[3]);
        *reinterpret_cast<float4*>(&out[obase + 3 * NZD + c0]) = make_float4(vZ[0],vZ[1],vZ[2],vZ[3]);
        *reinterpret_cast<float4*>(&out[obase + 4 * NZD + c0]) = make_float4(vD[0],vD[1],vD[2],vD[3]);
    }

    const float* KzBase = Kz + (size_t)si * (2 * NWN * LWN + 2) * (NZD + 1);
    const float* I0row  = I0 + (size_t)si * (NWN * LWN + 1);

    // ---- matrix-dependent factors, rebuilt every 4 steps ----
    float ivm[NL], qf[NL];          // Thomas: Dt[j] = dd[j]*ivm[j] - qf[j]*Dt[j-1]
    float Aa[3], Cc[NL];            // backsub factors; Cc[3] = C3
    float E1[3], E2[3], invbF;      // precomputed PCR elimination + final 1/b
    float Iez[NL];                  // I0d * exp(-XI*zT), per 8 steps
    float rap = 0.f;

    // prefetch first Kz row (hh = 0)
    float kzc[NL + 1];
    {
        const float* kzp = KzBase + (size_t)(2 * sw0) * (NZD + 1);
        #pragma unroll
        for (int j = 0; j <= NL; ++j) kzc[j] = act ? kzp[c0 + j] : 0.f;
    }

    for (int k = 0; k < NSTEPS; ++k) {
        const int day = k >> 3, hh = k >> 2;

        if ((k & 3) == 0) {
            // ---- rebuild matrix factors (uses prefetched kzc) ----
            float ac[NL], cc[NL];
            #pragma unroll
            for (int j = 0; j < NL; ++j) {
                ac[j] = kAf[j] * kzc[j];
                cc[j] = kCf[j] * kzc[j + 1];
            }
            // prefetch next Kz row (consumed 4 steps later; row hh+1 always in-bounds)
            {
                const float* kzp = KzBase + (size_t)(2 * sw0 + hh + 1) * (NZD + 1);
                #pragma unroll
                for (int j = 0; j <= NL; ++j) kzc[j] = act ? kzp[c0 + j] : 0.f;
            }
            // per-lane Thomas LU factors (4 fast rcp)
            float iv = frcp(1.f - ac[0] - cc[0]);
            ivm[0] = iv; qf[0] = 0.f;
            float Ap = ac[0] * iv;            // A_[0]
            Cc[0] = cc[0] * iv;
            Aa[0] = Ap;
            #pragma unroll
            for (int j = 1; j < NL; ++j) {
                const float m = 1.f - ac[j] - cc[j] - ac[j] * Cc[j - 1];
                iv = frcp(m);
                ivm[j] = iv; qf[j] = ac[j] * iv;
                Ap = -qf[j] * Ap;             // A_[j]
                Cc[j] = cc[j] * iv;
                if (j < 3) Aa[j] = Ap;
            }
            // compose spike coefficients F,G: x0 = E - F*xm - G*x3
            float F = Aa[2], G = Cc[2];
            F = Aa[1] - Cc[1] * F;  G = -Cc[1] * G;
            F = Aa[0] - Cc[0] * F;  G = -Cc[0] * G;
            const float Fn = bperm(aP1, F);
            const float Gn = bperm(aP1, G);
            float aRv = Ap;                         // A_[3]
            float bRv = 1.f - Cc[3] * Fn;
            float cRv = -Cc[3] * Gn;
            if (!act) { aRv = 0.f; bRv = 1.f; cRv = 0.f; }
            // 3 PCR rounds: precompute e1,e2 (coupling ~1e-2 -> 1e-16 after 3 rounds)
            #pragma unroll
            for (int r = 0; r < 3; ++r) {
                const float ib  = frcp(bRv);
                const float am  = bperm(aUp[r], aRv);
                const float ibm = bperm(aUp[r], ib);
                const float cm  = bperm(aUp[r], cRv);
                const float ap  = bperm(aDn[r], aRv);
                const float ibp = bperm(aDn[r], ib);
                const float cp  = bperm(aDn[r], cRv);
                const float e1 = -aRv * ibm;        // ==0 at lower edge (aRv==0 there)
                const float e2 = -cRv * ibp;        // ==0 at upper edge
                bRv = bRv + e1 * cm + e2 * ap;
                aRv = e1 * am;
                cRv = e2 * cp;
                E1[r] = e1; E2[r] = e2;
            }
            invbF = frcp(bRv);
        }
        if ((k & 7) == 0) {
            const float I0d = I0row[sw0 + day];
            #pragma unroll
            for (int j = 0; j < NL; ++j) Iez[j] = I0d * ezT[j];
            const float sw = subw[wi * LWN + day + 1];
            rap = 0.05f * (fminf(fmaxf(sw - 30.f, 0.f), 1.f)
                         - fminf(fmaxf(sw - 60.f, 0.f), 1.f));
        }

        // ---- cumsum of P*dzT: local prefix + 6-shuffle wave scan ----
        float cl[NL];
        float run = 0.f;
        #pragma unroll
        for (int j = 0; j < NL; ++j) { run += vP[j] * dzT[j]; cl[j] = run; }
        float pref = run;
        #pragma unroll
        for (int r = 0; r < 6; ++r) {
            const float t = bperm(aSc[r], pref);
            pref += (lane >= (1 << r)) ? t : 0.f;
        }
        pref -= run;   // exclusive prefix of lane totals

        // ---- bio tendencies + RHS (native exp/rcp/rsq) ----
        float dd[5][NL];
        #pragma unroll
        for (int j = 0; j < NL; ++j) {
            const float csum = pref + cl[j];
            const float It   = Iez[j] * __expf(-ZETA * csum);
            const float aIt  = pa * It;
            const float Gg   = ETA * aIt * frsq(ETA * ETA + aIt * aIt);
            const float fN   = vN[j] * frcp(KAP + vN[j]);
            const float fA   = vA[j] * frcp(KAP + vA[j]);
            const float eP   = __expf(-PSI * vA[j]);
            const float graz = prho * (1.f - __expf(-LAM * vP[j])) * vZ[j];
            const float bN = MU * vA[j] - Gg * eP * vP[j] * fN;
            const float bA = pvar * vD[j] + pGam * vZ[j] - Gg * vP[j] * fA - MU * vA[j];
            const float bP = Gg * vP[j] * (eP * fN + fA) - graz - pXi * vP[j];
            const float bZ = (1.f - pgam) * graz - pGam * vZ[j];
            const float bD = pgam * graz + pXi * vP[j] - pvar * vD[j];
            dd[0][j] = vN[j] + DT * bN;
            dd[1][j] = vA[j] + DT * bA;
            dd[2][j] = vP[j] + DT * bP;
            dd[3][j] = vZ[j] + DT * bZ;
            dd[4][j] = vD[j] + DT * bD;
        }

        // ---- per-lane d-sweep (factors precomputed; FMA only) ----
        float Dt[5][NL];
        #pragma unroll
        for (int t = 0; t < 5; ++t) {
            Dt[t][0] = dd[t][0] * ivm[0];
            #pragma unroll
            for (int j = 1; j < NL; ++j)
                Dt[t][j] = dd[t][j] * ivm[j] - qf[j] * Dt[t][j - 1];
        }

        // ---- reduced RHS + 3 precomputed PCR-d rounds ----
        float dR[5];
        #pragma unroll
        for (int t = 0; t < 5; ++t) {
            const float Ec = Dt[t][0] - Cc[0] * (Dt[t][1] - Cc[1] * Dt[t][2]);
            const float En = bperm(aP1, Ec);
            dR[t] = Dt[t][3] - Cc[3] * En;
        }
        #pragma unroll
        for (int r = 0; r < 3; ++r) {
            #pragma unroll
            for (int t = 0; t < 5; ++t) {
                const float dm = bperm(aUp[r], dR[t]);
                const float dp = bperm(aDn[r], dR[t]);
                dR[t] += E1[r] * dm + E2[r] * dp;
            }
        }

        // ---- solution + back-substitution ----
        float X[5][NL];
        #pragma unroll
        for (int t = 0; t < 5; ++t) {
            const float y  = dR[t] * invbF;
            const float xm = bperm(aM1, y);     // lane 0: Aa[]==0 kills xm
            X[t][3] = y;
            X[t][2] = Dt[t][2] - Aa[2] * xm - Cc[2] * X[t][3];
            X[t][1] = Dt[t][1] - Aa[1] * xm - Cc[1] * X[t][2];
            X[t][0] = Dt[t][0] - Aa[0] * xm - Cc[0] * X[t][1];
        }

        // ---- WENO3-Z sediment flux ----
        float q[NL];
        #pragma unroll
        for (int j = 0; j < NL; ++j) q[j] = X[4][j] * dzT[j];
        const float qm2 = bperm(aM1, q[2]);
        const float qm1 = bperm(aM1, q[3]);
        float f0 = (lane == 0) ? 0.f            : weno3z_f(qm2, qm1, q[0]) * swN[0];
        float f1 = (lane == 0) ? sedc * X[4][0] : weno3z_f(qm1, q[0], q[1]) * swN[1];
        float f2 = weno3z_f(q[0], q[1], q[2]) * swN[2];
        float f3 = weno3z_f(q[1], q[2], q[3]) * swN[3];
        const float f0n = bperm(aP1, f0);
        float f4 = (lane == ACTL - 1) ? sedc * X[4][3] : f0n;

        // ---- commit state (+NO3 relaxation) ----
        const float fs[NL + 1] = { f0, f1, f2, f3, f4 };
        #pragma unroll
        for (int j = 0; j < NL; ++j) {
            vD[j] = X[4][j] + (fs[j] - fs[j + 1]) * DTdz[j];
            vN[j] = X[0][j] + (pbet - X[0][j]) * rap;
            vA[j] = X[1][j]; vP[j] = X[2][j]; vZ[j] = X[3][j];
        }

        if (((k + 1) & 7) == 0 && act) {
            const int fr = (k + 1) >> 3;
            const size_t ob = obase + (size_t)fr * (5 * NZD) + c0;
            *reinterpret_cast<float4*>(&out[ob + 0 * NZD]) = make_float4(vN[0],vN[1],vN[2],vN[3]);
            *reinterpret_cast<float4*>(&out[ob + 1 * NZD]) = make_float4(vA[0],vA[1],vA[2],vA[3]);
            *reinterpret_cast<float4*>(&out[ob + 2 * NZD]) = make_float4(vP[0],vP[1],vP[2],vP[3]);
            *reinterpret_cast<float4*>(&out[ob + 3 * NZD]) = make_float4(vZ[0],vZ[1],vZ[2],vZ[3]);
            *reinterpret_cast<float4*>(&out[ob + 4 * NZD]) = make_float4(vD[0],vD[1],vD[2],vD[3]);
        }
    }
}

extern "C" void kernel_launch(void* const* d_in, const int* in_sizes, int n_in,
                              void* d_out, int out_size, void* d_ws, size_t ws_size,
                              hipStream_t stream) {
    const float* Kz    = (const float*)d_in[0];
    const float* I0    = (const float*)d_in[1];
    const float* alpha = (const float*)d_in[2];
    const float* Xi    = (const float*)d_in[3];
    const float* rho   = (const float*)d_in[4];
    const float* gam   = (const float*)d_in[5];
    const float* Gam   = (const float*)d_in[6];
    const float* varp  = (const float*)d_in[7];
    const float* omg   = (const float*)d_in[8];
    const float* bet   = (const float*)d_in[9];
    const float* N0    = (const float*)d_in[10];
    const float* A0    = (const float*)d_in[11];
    const float* P0    = (const float*)d_in[12];
    const float* Z0    = (const float*)d_in[13];
    const float* Dd0   = (const float*)d_in[14];
    const float* sbw   = (const float*)d_in[15];
    const float* zTp   = (const float*)d_in[16];
    const float* zwp   = (const float*)d_in[17];
    float* out = (float*)d_out;

    dim3 grid(NSC * NWN);   // 768 waves = 3 blocks/CU
    dim3 block(64);
    hipLaunchKernelGGL(nnpzd_wave, grid, block, 0, stream,
                       Kz, I0, alpha, Xi, rho, gam, Gam, varp, omg, bet,
                       N0, A0, P0, Z0, Dd0, sbw, zTp, zwp, out);
}

// Round 4
// 75.448 us; speedup vs baseline: 3.1909x; 1.0258x over previous
//
#include <hip/hip_runtime.h>

#define NSC 64      // Ns
#define NWN 12      // nw
#define LWN 6       // lw
#define NZD 200     // Nz
#define NSTEPS 40   // (lw-1)*SPD
#define NFRAMES 6
#define NL 4        // cells per lane
#define ACTL 50     // active lanes (50*4 = 200)

__device__ __forceinline__ float frcp(float x) { return __builtin_amdgcn_rcpf(x); }
__device__ __forceinline__ float frsq(float x) { return __builtin_amdgcn_rsqf(x); }
__device__ __forceinline__ float bperm(int addr, float v) {
    return __int_as_float(__builtin_amdgcn_ds_bpermute(addr, __float_as_int(v)));
}

// DPP-assisted add: x + shifted(x), constant control fields.
template<int CTRL, int RMASK, bool BC>
__device__ __forceinline__ float dppadd(float x) {
    const int t = __builtin_amdgcn_update_dpp(0, __float_as_int(x), CTRL, RMASK, 0xf, BC);
    return x + __int_as_float(t);
}
// wave64 inclusive scan, 6 VALU-DPP ops (row_shr 1,2,4,8; bcast15 rows1,3; bcast31 rows2,3)
__device__ __forceinline__ float wave_iscan(float x) {
    x = dppadd<0x111, 0xf, true>(x);
    x = dppadd<0x112, 0xf, true>(x);
    x = dppadd<0x114, 0xf, true>(x);
    x = dppadd<0x118, 0xf, true>(x);
    x = dppadd<0x142, 0xa, false>(x);
    x = dppadd<0x143, 0xc, false>(x);
    return x;
}

__device__ __forceinline__ float weno3z_f(float qm, float q0, float qp) {
    const float qi1 = -0.5f * qm + 1.5f * q0;
    const float qi2 = 0.5f * (q0 + qp);
    const float b1 = (q0 - qm) * (q0 - qm);
    const float b2 = (qp - q0) * (qp - q0);
    const float tau = fabsf(b2 - b1);
    const float w1 = (1.f / 3.f) * (1.f + tau * frcp(b1 + 1e-14f));
    const float w2 = (2.f / 3.f) * (1.f + tau * frcp(b2 + 1e-14f));
    return (w1 * qi1 + w2 * qi2) * frcp(w1 + w2);
}

__global__ __launch_bounds__(64) void nnpzd_wave(
    const float* __restrict__ Kz, const float* __restrict__ I0,
    const float* __restrict__ alpha_p, const float* __restrict__ Xi_p,
    const float* __restrict__ rho_p, const float* __restrict__ gamma_p,
    const float* __restrict__ Gamma_p, const float* __restrict__ varphi_p,
    const float* __restrict__ omega_p, const float* __restrict__ beta_p,
    const float* __restrict__ NO3_0, const float* __restrict__ NH4_0,
    const float* __restrict__ P_0, const float* __restrict__ Z_0,
    const float* __restrict__ D_0, const float* __restrict__ subw,
    const float* __restrict__ zT, const float* __restrict__ zw,
    float* __restrict__ out)
{
    const float XI = 0.067f, ZETA = 0.0095f, LAM = 0.06f, PSI = 1.46f;
    const float MU = 0.25f, ETA = 1.5f, KAP = 1.0f, DT = 0.125f;

    const int col  = blockIdx.x;            // one column per wave
    const int si   = col / NWN;
    const int wi   = col - si * NWN;
    const int lane = threadIdx.x;           // blockDim = 64 = one wave
    const bool act = lane < ACTL;
    const int  c0  = lane * NL;

    // ---- precomputed bpermute byte addresses ----
    const int aM1 = ((lane > 0) ? lane - 1 : 0) * 4;
    const int aP1 = ((lane < 63) ? lane + 1 : 63) * 4;
    int aUp[2], aDn[2];
    #pragma unroll
    for (int r = 0; r < 2; ++r) {
        const int off = 1 << r;
        aUp[r] = ((lane >= off) ? lane - off : 0) * 4;
        aDn[r] = ((lane + off < 64) ? lane + off : 63) * 4;
    }
    int aG[8];                                // gather offsets -4..+3
    #pragma unroll
    for (int i = 0; i < 8; ++i) {
        int l = lane + (i - 4);
        l = (l < 0) ? 0 : ((l > 63) ? 63 : l);
        aG[i] = l * 4;
    }

    const float pa   = alpha_p[si];
    const float pXi  = Xi_p[si];
    const float prho = rho_p[si];
    const float pgam = gamma_p[si];
    const float pGam = Gamma_p[si];
    const float pvar = varphi_p[si];
    const float sedc = omega_p[si];
    const float pbet = beta_p[si];
    const int   sw0  = (int)subw[wi * LWN];

    // ---- per-lane constant geometry ----
    float dzT[NL], DTdz[NL], ezT[NL], kAf[NL], kCf[NL], swN[NL], swN4;
    {
        float dzw_[NL + 2];
        #pragma unroll
        for (int j = 0; j <= NL + 1; ++j) {
            const int i = act ? (c0 + j) : 0;
            dzw_[j] = (i == 0)   ? 0.5f * (zw[1] - zw[0])
                    : (i >= NZD) ? 0.5f * (zw[NZD] - zw[NZD - 1])
                                 : (zT[i] - zT[i - 1]);
        }
        #pragma unroll
        for (int j = 0; j < NL; ++j) {
            const int i = act ? (c0 + j) : 0;
            const float dz = zw[i + 1] - zw[i];
            dzT[j]  = dz;
            DTdz[j] = act ? (DT / dz) : 0.f;
            ezT[j]  = expf(-XI * zT[i]);
            kAf[j]  = (act && (c0 + j) >= 1)       ? (-DT / (dz * dzw_[j]))     : 0.f;
            kCf[j]  = (act && (c0 + j) <= NZD - 2) ? (-DT / (dz * dzw_[j + 1])) : 0.f;
            swN[j]  = act ? (sedc / dzw_[j]) : 0.f;
        }
        swN4 = act ? (sedc / dzw_[NL]) : 0.f;   // interface c0+4 (interior lanes)
    }

    // ---- initial state (float4 loads) ----
    float vN[NL], vA[NL], vP[NL], vZ[NL], vD[NL];
    {
        const size_t ib = (size_t)col * NZD + c0;
        if (act) {
            const float4 n4 = *reinterpret_cast<const float4*>(&NO3_0[ib]);
            const float4 a4 = *reinterpret_cast<const float4*>(&NH4_0[ib]);
            const float4 p4 = *reinterpret_cast<const float4*>(&P_0[ib]);
            const float4 z4 = *reinterpret_cast<const float4*>(&Z_0[ib]);
            const float4 d4 = *reinterpret_cast<const float4*>(&D_0[ib]);
            vN[0]=n4.x; vN[1]=n4.y; vN[2]=n4.z; vN[3]=n4.w;
            vA[0]=a4.x; vA[1]=a4.y; vA[2]=a4.z; vA[3]=a4.w;
            vP[0]=p4.x; vP[1]=p4.y; vP[2]=p4.z; vP[3]=p4.w;
            vZ[0]=z4.x; vZ[1]=z4.y; vZ[2]=z4.z; vZ[3]=z4.w;
            vD[0]=d4.x; vD[1]=d4.y; vD[2]=d4.z; vD[3]=d4.w;
        } else {
            #pragma unroll
            for (int j = 0; j < NL; ++j) { vN[j]=vA[j]=vP[j]=vZ[j]=vD[j]=0.f; }
        }
    }

    // frame 0
    const size_t obase = (size_t)col * (NFRAMES * 5 * NZD);
    if (act) {
        *reinterpret_cast<float4*>(&out[obase + 0 * NZD + c0]) = make_float4(vN[0],vN[1],vN[2],vN[3]);
        *reinterpret_cast<float4*>(&out[obase + 1 * NZD + c0]) = make_float4(vA[0],vA[1],vA[2],vA[3]);
        *reinterpret_cast<float4*>(&out[obase + 2 * NZD + c0]) = make_float4(vP[0],vP[1],vP[2],vP[3]);
        *reinterpret_cast<float4*>(&out[obase + 3 * NZD + c0]) = make_float4(vZ[0],vZ[1],vZ[2],vZ[3]);
        *reinterpret_cast<float4*>(&out[obase + 4 * NZD + c0]) = make_float4(vD[0],vD[1],vD[2],vD[3]);
    }

    const float* KzBase = Kz + (size_t)si * (2 * NWN * LWN + 2) * (NZD + 1);
    const float* I0row  = I0 + (size_t)si * (NWN * LWN + 1);

    // ---- factors rebuilt every 4 steps ----
    float t00, t10, t11, t20, t21, t22, t30, t31, t32, t33;   // Dt = T * dd
    float ecf0, ecf1, ecf2;                                   // Ec = ecf . dd
    float aa0, aa1, aa2, cl0, cl1, cl2, cl3;                  // backsub factors
    float Wy[7], Wx[7];                                       // stencil weights
    float Iez[NL];
    float rap = 0.f;

    // prefetch first Kz row
    float kzc[NL + 1];
    {
        const float* kzp = KzBase + (size_t)(2 * sw0) * (NZD + 1);
        #pragma unroll
        for (int j = 0; j <= NL; ++j) kzc[j] = act ? kzp[c0 + j] : 0.f;
    }

    for (int k = 0; k < NSTEPS; ++k) {
        const int day = k >> 3, hh = k >> 2;

        if ((k & 3) == 0) {
            // ---- tridiagonal coefficients from prefetched Kz ----
            float ac[NL], cc[NL];
            #pragma unroll
            for (int j = 0; j < NL; ++j) {
                ac[j] = kAf[j] * kzc[j];
                cc[j] = kCf[j] * kzc[j + 1];
            }
            {   // prefetch next Kz row (consumed 4 steps later)
                const float* kzp = KzBase + (size_t)(2 * sw0 + hh + 1) * (NZD + 1);
                #pragma unroll
                for (int j = 0; j <= NL; ++j) kzc[j] = act ? kzp[c0 + j] : 0.f;
            }
            // Thomas LU factors
            float iv0 = frcp(1.f - ac[0] - cc[0]);
            cl0 = cc[0] * iv0;
            aa0 = ac[0] * iv0;
            t00 = iv0;
            float m1 = 1.f - ac[1] - cc[1] - ac[1] * cl0;
            float iv1 = frcp(m1);
            float qf1 = ac[1] * iv1;
            cl1 = cc[1] * iv1;
            aa1 = -qf1 * aa0;
            t11 = iv1; t10 = -qf1 * t00;
            float m2 = 1.f - ac[2] - cc[2] - ac[2] * cl1;
            float iv2 = frcp(m2);
            float qf2 = ac[2] * iv2;
            cl2 = cc[2] * iv2;
            aa2 = -qf2 * aa1;
            t22 = iv2; t21 = -qf2 * t11; t20 = -qf2 * t10;
            float m3 = 1.f - ac[3] - cc[3] - ac[3] * cl2;
            float iv3 = frcp(m3);
            float qf3 = ac[3] * iv3;
            cl3 = cc[3] * iv3;
            const float aa3 = -qf3 * aa2;
            t33 = iv3; t32 = -qf3 * t22; t31 = -qf3 * t21; t30 = -qf3 * t20;
            // Ec = Dt0 - cl0*Dt1 + cl0*cl1*Dt2
            const float c01 = cl0 * cl1;
            ecf0 = t00 - cl0 * t10 + c01 * t20;
            ecf1 = -cl0 * t11 + c01 * t21;
            ecf2 = c01 * t22;
            // spike coefficients
            const float F = aa0 - cl0 * (aa1 - cl1 * aa2);
            const float G = cl0 * cl1 * cl2;
            const float Fn = bperm(aP1, F);
            const float Gn = bperm(aP1, G);
            float aR = aa3;
            float bR = 1.f - cl3 * Fn;
            float cR = -cl3 * Gn;
            if (!act) { aR = 0.f; bR = 1.f; cR = 0.f; }
            // PCR round 1 (offset 1)
            const float ib  = frcp(bR);
            const float am  = bperm(aUp[0], aR), ibm = bperm(aUp[0], ib), cm = bperm(aUp[0], cR);
            const float ap  = bperm(aDn[0], aR), ibp = bperm(aDn[0], ib), cp = bperm(aDn[0], cR);
            const float E1 = -aR * ibm;           // 0 at/below lower edge (aR==0)
            const float E2 = -cR * ibp;           // 0 at/above upper edge
            const float b1 = bR + E1 * cm + E2 * ap;
            const float a1 = E1 * am;
            const float c1 = E2 * cp;
            // PCR round 2 (offset 2)
            const float ib1  = frcp(b1);
            const float am2  = bperm(aUp[1], a1), ib1m = bperm(aUp[1], ib1), cm2 = bperm(aUp[1], c1);
            const float ap2  = bperm(aDn[1], a1), ib1p = bperm(aDn[1], ib1), cp2 = bperm(aDn[1], c1);
            const float E1p = -a1 * ib1m;
            const float E2p = -c1 * ib1p;
            const float b2 = b1 + E1p * cm2 + E2p * ap2;
            const float invbF = frcp(b2);
            // neighbor E's at +-2 for the fused stencil
            const float E1m2 = bperm(aUp[1], E1);
            const float E2m2 = bperm(aUp[1], E2);
            const float E1p2 = bperm(aDn[1], E1);
            const float E2p2 = bperm(aDn[1], E2);
            // w[m], m = -3..3  ->  Wy[i] = invbF * w[i-3]
            Wy[0] = invbF * (E1p * E1m2);
            Wy[1] = invbF * E1p;
            Wy[2] = invbF * (E1 + E1p * E2m2);
            Wy[3] = invbF;
            Wy[4] = invbF * (E2 + E2p * E1p2);
            Wy[5] = invbF * E2p;
            Wy[6] = invbF * (E2p * E2p2);
            // Wx[n+4] = Wy(l-1)[n+1+3], n = -4..2  ->  shift of the same 7 weights
            #pragma unroll
            for (int i = 0; i < 7; ++i) Wx[i] = bperm(aM1, Wy[i]);
        }
        if ((k & 7) == 0) {
            const float I0d = I0row[sw0 + day];
            #pragma unroll
            for (int j = 0; j < NL; ++j) Iez[j] = I0d * ezT[j];
            const float sw = subw[wi * LWN + day + 1];
            rap = 0.05f * (fminf(fmaxf(sw - 30.f, 0.f), 1.f)
                         - fminf(fmaxf(sw - 60.f, 0.f), 1.f));
        }

        // ---- cumsum of P*dzT: local prefix + DPP wave scan ----
        float cl_[NL];
        float run = 0.f;
        #pragma unroll
        for (int j = 0; j < NL; ++j) { run += vP[j] * dzT[j]; cl_[j] = run; }
        const float pref = wave_iscan(run) - run;    // exclusive prefix of lane totals

        // ---- bio tendencies + RHS ----
        float dd[5][NL];
        #pragma unroll
        for (int j = 0; j < NL; ++j) {
            const float csum = pref + cl_[j];
            const float It   = Iez[j] * __expf(-ZETA * csum);
            const float aIt  = pa * It;
            const float Gg   = ETA * aIt * frsq(ETA * ETA + aIt * aIt);
            const float fN   = vN[j] * frcp(KAP + vN[j]);
            const float fA   = vA[j] * frcp(KAP + vA[j]);
            const float eP   = __expf(-PSI * vA[j]);
            const float graz = prho * (1.f - __expf(-LAM * vP[j])) * vZ[j];
            const float bN = MU * vA[j] - Gg * eP * vP[j] * fN;
            const float bA = pvar * vD[j] + pGam * vZ[j] - Gg * vP[j] * fA - MU * vA[j];
            const float bP = Gg * vP[j] * (eP * fN + fA) - graz - pXi * vP[j];
            const float bZ = (1.f - pgam) * graz - pGam * vZ[j];
            const float bD = pgam * graz + pXi * vP[j] - pvar * vD[j];
            dd[0][j] = vN[j] + DT * bN;
            dd[1][j] = vA[j] + DT * bA;
            dd[2][j] = vP[j] + DT * bP;
            dd[3][j] = vZ[j] + DT * bZ;
            dd[4][j] = vD[j] + DT * bD;
        }

        // ---- Ec first (issues the En shuffle ASAP), then Dt3 / dR ----
        float Ec[5], En[5];
        #pragma unroll
        for (int t = 0; t < 5; ++t) {
            Ec[t] = ecf0 * dd[t][0] + ecf1 * dd[t][1] + ecf2 * dd[t][2];
            En[t] = bperm(aP1, Ec[t]);
        }
        float dR[5];
        #pragma unroll
        for (int t = 0; t < 5; ++t) {
            const float Dt3 = t30 * dd[t][0] + t31 * dd[t][1] + t32 * dd[t][2] + t33 * dd[t][3];
            dR[t] = Dt3 - cl3 * En[t];
        }

        // ---- single-level gather (offsets -4..+3) + fused 2-round PCR stencil ----
        float y[5], xm[5];
        #pragma unroll
        for (int t = 0; t < 5; ++t) {
            float g[8];
            #pragma unroll
            for (int i = 0; i < 8; ++i) g[i] = bperm(aG[i], dR[t]);
            y[t]  = Wy[0]*g[1] + Wy[1]*g[2] + Wy[2]*g[3] + Wy[3]*g[4]
                  + Wy[4]*g[5] + Wy[5]*g[6] + Wy[6]*g[7];
            xm[t] = Wx[0]*g[0] + Wx[1]*g[1] + Wx[2]*g[2] + Wx[3]*g[3]
                  + Wx[4]*g[4] + Wx[5]*g[5] + Wx[6]*g[6];
        }

        // ---- back-substitution (Dt0..Dt2 via precomputed T) ----
        float X[5][NL];
        #pragma unroll
        for (int t = 0; t < 5; ++t) {
            const float Dt0 = t00 * dd[t][0];
            const float Dt1 = t10 * dd[t][0] + t11 * dd[t][1];
            const float Dt2 = t20 * dd[t][0] + t21 * dd[t][1] + t22 * dd[t][2];
            X[t][3] = y[t];
            X[t][2] = Dt2 - aa2 * xm[t] - cl2 * X[t][3];
            X[t][1] = Dt1 - aa1 * xm[t] - cl1 * X[t][2];
            X[t][0] = Dt0 - aa0 * xm[t] - cl0 * X[t][1];
        }

        // ---- WENO3-Z sediment flux (one parallel shuffle level) ----
        float q[NL];
        #pragma unroll
        for (int j = 0; j < NL; ++j) q[j] = X[4][j] * dzT[j];
        const float qm2 = bperm(aM1, q[2]);
        const float qm1 = bperm(aM1, q[3]);
        const float qn0 = bperm(aP1, q[0]);
        const float f0 = (lane == 0) ? 0.f            : weno3z_f(qm2, qm1, q[0]) * swN[0];
        const float f1 = (lane == 0) ? sedc * X[4][0] : weno3z_f(qm1, q[0], q[1]) * swN[1];
        const float f2 = weno3z_f(q[0], q[1], q[2]) * swN[2];
        const float f3 = weno3z_f(q[1], q[2], q[3]) * swN[3];
        const float f4 = (lane == ACTL - 1) ? sedc * X[4][3]
                                            : weno3z_f(q[2], q[3], qn0) * swN4;

        // ---- commit state (+NO3 relaxation) ----
        const float fs[NL + 1] = { f0, f1, f2, f3, f4 };
        #pragma unroll
        for (int j = 0; j < NL; ++j) {
            vD[j] = X[4][j] + (fs[j] - fs[j + 1]) * DTdz[j];
            vN[j] = X[0][j] + (pbet - X[0][j]) * rap;
            vA[j] = X[1][j]; vP[j] = X[2][j]; vZ[j] = X[3][j];
        }

        if (((k + 1) & 7) == 0 && act) {
            const int fr = (k + 1) >> 3;
            const size_t ob = obase + (size_t)fr * (5 * NZD) + c0;
            *reinterpret_cast<float4*>(&out[ob + 0 * NZD]) = make_float4(vN[0],vN[1],vN[2],vN[3]);
            *reinterpret_cast<float4*>(&out[ob + 1 * NZD]) = make_float4(vA[0],vA[1],vA[2],vA[3]);
            *reinterpret_cast<float4*>(&out[ob + 2 * NZD]) = make_float4(vP[0],vP[1],vP[2],vP[3]);
            *reinterpret_cast<float4*>(&out[ob + 3 * NZD]) = make_float4(vZ[0],vZ[1],vZ[2],vZ[3]);
            *reinterpret_cast<float4*>(&out[ob + 4 * NZD]) = make_float4(vD[0],vD[1],vD[2],vD[3]);
        }
    }
}

extern "C" void kernel_launch(void* const* d_in, const int* in_sizes, int n_in,
                              void* d_out, int out_size, void* d_ws, size_t ws_size,
                              hipStream_t stream) {
    const float* Kz    = (const float*)d_in[0];
    const float* I0    = (const float*)d_in[1];
    const float* alpha = (const float*)d_in[2];
    const float* Xi    = (const float*)d_in[3];
    const float* rho   = (const float*)d_in[4];
    const float* gam   = (const float*)d_in[5];
    const float* Gam   = (const float*)d_in[6];
    const float* varp  = (const float*)d_in[7];
    const float* omg   = (const float*)d_in[8];
    const float* bet   = (const float*)d_in[9];
    const float* N0    = (const float*)d_in[10];
    const float* A0    = (const float*)d_in[11];
    const float* P0    = (const float*)d_in[12];
    const float* Z0    = (const float*)d_in[13];
    const float* Dd0   = (const float*)d_in[14];
    const float* sbw   = (const float*)d_in[15];
    const float* zTp   = (const float*)d_in[16];
    const float* zwp   = (const float*)d_in[17];
    float* out = (float*)d_out;

    dim3 grid(NSC * NWN);
    dim3 block(64);
    hipLaunchKernelGGL(nnpzd_wave, grid, block, 0, stream,
                       Kz, I0, alpha, Xi, rho, gam, Gam, varp, omg, bet,
                       N0, A0, P0, Z0, Dd0, sbw, zTp, zwp, out);
}